// Round 1
// baseline (3597.874 us; speedup 1.0000x reference)
//
#include <hip/hip_runtime.h>
#include <math.h>

#define N 4096
#define D 128
#define FEPS 1e-5f

// ---------------- reduction helpers ----------------
__device__ __forceinline__ double block_reduce256(double v, double* red) {
    int t = threadIdx.x;
    red[t] = v;
    __syncthreads();
    #pragma unroll
    for (int s = 128; s > 0; s >>= 1) {
        if (t < s) red[t] += red[t + s];
        __syncthreads();
    }
    double r = red[0];
    __syncthreads();
    return r;
}

// ---------------- gather + row norms ----------------
__global__ void gather_energy(const float* __restrict__ W, const int* __restrict__ idx,
                              float* __restrict__ E, float* __restrict__ energy) {
    int i = blockIdx.x, t = threadIdx.x;
    float v = W[(size_t)idx[i] * D + t];
    E[(size_t)i * D + t] = v;
    float sq = v * v;
    #pragma unroll
    for (int o = 32; o > 0; o >>= 1) sq += __shfl_down(sq, o);
    __shared__ float s2[2];
    if ((t & 63) == 0) s2[t >> 6] = sq;
    __syncthreads();
    if (t == 0) energy[i] = sqrtf(s2[0] + s2[1]);
}

// ---------------- trans row sums ----------------
__global__ void row_sums(const float* __restrict__ T, float* __restrict__ trow) {
    int i = blockIdx.x, t = threadIdx.x;
    float s = 0.f;
    for (int j = t; j < N; j += 256) s += T[(size_t)i * N + j];
    #pragma unroll
    for (int o = 32; o > 0; o >>= 1) s += __shfl_down(s, o);
    __shared__ float sm[4];
    if ((t & 63) == 0) sm[t >> 6] = s;
    __syncthreads();
    if (t == 0) trow[i] = sm[0] + sm[1] + sm[2] + sm[3];
}

// ---------------- trans col sums (tcol must be zeroed) ----------------
__global__ void col_sums(const float* __restrict__ T, float* __restrict__ tcol) {
    int j = blockIdx.x * 256 + threadIdx.x;
    int r0 = blockIdx.y * (N / 32);
    float s = 0.f;
    for (int i = 0; i < N / 32; ++i) s += T[(size_t)(r0 + i) * N + j];
    atomicAdd(&tcol[j], s);
}

// ---------------- cosine-cost kernels ----------------
// SELF=1: cost = 1-exp(-5(1-cos)), store to outC, accumulate
//         sc[0] += (cost-ref)^2*exp(-ref) ; sc[1] += cost^2*mu[col]*tsum[row]
// SELF=0: cost = 1-exp(-(1-cos)), accumulate sc[3] += cost*trans[row,col]
template <int SELF>
__global__ __launch_bounds__(256) void cost_kernel(
        const float* __restrict__ EA, const float* __restrict__ EB,
        const float* __restrict__ ea, const float* __restrict__ eb,
        const float* __restrict__ ref_or_trans,
        const float* __restrict__ mu, const float* __restrict__ tsum,
        float* __restrict__ outC, double* __restrict__ sc) {
    __shared__ float As[16][68];
    __shared__ float Bs[16][68];
    __shared__ double red[256];
    int t = threadIdx.x;
    int tx = t & 15, ty = t >> 4;
    int bi = blockIdx.y * 64, bj = blockIdx.x * 64;
    float acc[4][4] = {};
    for (int kk = 0; kk < D; kk += 16) {
        #pragma unroll
        for (int r = 0; r < 4; ++r) {
            int e = t + 256 * r;
            int ar = e >> 4, ac = e & 15;
            As[ac][ar] = EA[(size_t)(bi + ar) * D + kk + ac];
            Bs[ac][ar] = EB[(size_t)(bj + ar) * D + kk + ac];
        }
        __syncthreads();
        #pragma unroll
        for (int k = 0; k < 16; ++k) {
            float4 av = *(const float4*)&As[k][ty * 4];
            float4 bv = *(const float4*)&Bs[k][tx * 4];
            float a[4] = {av.x, av.y, av.z, av.w};
            float b[4] = {bv.x, bv.y, bv.z, bv.w};
            #pragma unroll
            for (int u = 0; u < 4; ++u)
                #pragma unroll
                for (int v = 0; v < 4; ++v)
                    acc[u][v] = fmaf(a[u], b[v], acc[u][v]);
        }
        __syncthreads();
    }
    float eav[4], ebv[4];
    #pragma unroll
    for (int u = 0; u < 4; ++u) eav[u] = ea[bi + ty * 4 + u];
    #pragma unroll
    for (int v = 0; v < 4; ++v) ebv[v] = eb[bj + tx * 4 + v];

    double l1 = 0.0, l2 = 0.0;
    #pragma unroll
    for (int u = 0; u < 4; ++u) {
        int ri = bi + ty * 4 + u;
        #pragma unroll
        for (int v = 0; v < 4; ++v) {
            int ci = bj + tx * 4 + v;
            size_t id = (size_t)ri * N + ci;
            float denom = eav[u] * ebv[v] + FEPS;
            float cosv = acc[u][v] / denom;
            if (SELF) {
                float c = 1.f - expf(-5.f * (1.f - cosv));
                outC[id] = c;
                float rc = ref_or_trans[id];
                float dd = c - rc;
                l1 += (double)(dd * dd * expf(-rc));
                l2 += (double)(c * c) * (double)mu[ci] * (double)tsum[ri];
            } else {
                float c = 1.f - expf(-(1.f - cosv));
                l1 += (double)c * (double)ref_or_trans[id];
            }
        }
    }
    double s1 = block_reduce256(l1, red);
    if (SELF) {
        double s2v = block_reduce256(l2, red);
        if (t == 0) { atomicAdd(&sc[0], s1); atomicAdd(&sc[1], s2v); }
    } else {
        if (t == 0) atomicAdd(&sc[3], s1);
    }
}

// ---------------- fp32 NN GEMM, 128x128 tile, 8x8 microtile ----------------
// STORE=1: C = A@B.  STORE=0: sc += <A@B, Dm>_F (C unused)
template <int STORE>
__global__ __launch_bounds__(256) void gemm_nn(
        const float* __restrict__ A, const float* __restrict__ B,
        float* __restrict__ C, const float* __restrict__ Dm,
        double* __restrict__ acc_out) {
    __shared__ float As[16][132];
    __shared__ float Bs[16][132];
    __shared__ double red[256];
    int t = threadIdx.x;
    int tx = t & 15, ty = t >> 4;
    int bi = blockIdx.y * 128, bj = blockIdx.x * 128;
    float acc[8][8] = {};
    for (int kk = 0; kk < N; kk += 16) {
        #pragma unroll
        for (int r = 0; r < 2; ++r) {
            int q = t + 256 * r;
            int arow = q >> 2, acq = (q & 3) * 4;
            float4 av = *(const float4*)&A[(size_t)(bi + arow) * N + kk + acq];
            As[acq + 0][arow] = av.x;
            As[acq + 1][arow] = av.y;
            As[acq + 2][arow] = av.z;
            As[acq + 3][arow] = av.w;
            int brow = q >> 5, bcq = (q & 31) * 4;
            *(float4*)&Bs[brow][bcq] = *(const float4*)&B[(size_t)(kk + brow) * N + bj + bcq];
        }
        __syncthreads();
        #pragma unroll
        for (int k = 0; k < 16; ++k) {
            float a[8], b[8];
            *(float4*)&a[0] = *(const float4*)&As[k][ty * 8];
            *(float4*)&a[4] = *(const float4*)&As[k][ty * 8 + 4];
            *(float4*)&b[0] = *(const float4*)&Bs[k][tx * 8];
            *(float4*)&b[4] = *(const float4*)&Bs[k][tx * 8 + 4];
            #pragma unroll
            for (int u = 0; u < 8; ++u)
                #pragma unroll
                for (int v = 0; v < 8; ++v)
                    acc[u][v] = fmaf(a[u], b[v], acc[u][v]);
        }
        __syncthreads();
    }
    if (STORE) {
        #pragma unroll
        for (int u = 0; u < 8; ++u) {
            int ri = bi + ty * 8 + u;
            #pragma unroll
            for (int v = 0; v < 8; v += 4) {
                int ci = bj + tx * 8 + v;
                *(float4*)&C[(size_t)ri * N + ci] = *(float4*)&acc[u][v];
            }
        }
    } else {
        double l = 0.0;
        #pragma unroll
        for (int u = 0; u < 8; ++u) {
            int ri = bi + ty * 8 + u;
            #pragma unroll
            for (int v = 0; v < 8; ++v) {
                int ci = bj + tx * 8 + v;
                l += (double)acc[u][v] * (double)Dm[(size_t)ri * N + ci];
            }
        }
        double s = block_reduce256(l, red);
        if (t == 0) atomicAdd(acc_out, s);
    }
}

// ---------------- orthogonality: sum((E^T E - I)^2) ----------------
__global__ void orth_kernel(const float* __restrict__ E, double* __restrict__ sc) {
    int a = blockIdx.x, b = threadIdx.x;
    float acc = 0.f;
    for (int i = 0; i < N; ++i)
        acc = fmaf(E[(size_t)i * D + a], E[(size_t)i * D + b], acc);
    if (a == b) acc -= 1.f;
    double v = (double)acc * (double)acc;
    #pragma unroll
    for (int o = 32; o > 0; o >>= 1) v += __shfl_down(v, o);
    __shared__ double sm[2];
    if ((b & 63) == 0) sm[b >> 6] = v;
    __syncthreads();
    if (b == 0) atomicAdd(&sc[4], sm[0] + sm[1]);
}

// ---------------- finalize ----------------
__global__ void finalize(const double* __restrict__ sc, float* __restrict__ out) {
    if (threadIdx.x == 0) {
        out[0] = (float)(sc[1] - 2.0 * sc[2]);  // d_gw = f1term+f2term - 2*<P,Q>
        out[1] = (float)sc[3];                  // d_w
        out[2] = (float)(sc[0] + sc[4]);        // regularizer
    }
}

extern "C" void kernel_launch(void* const* d_in, const int* in_sizes, int n_in,
                              void* d_out, int out_size, void* d_ws, size_t ws_size,
                              hipStream_t stream) {
    const int*   index1 = (const int*)d_in[0];
    const int*   index2 = (const int*)d_in[1];
    const float* trans  = (const float*)d_in[2];
    const float* mu_s   = (const float*)d_in[3];
    const float* mu_t   = (const float*)d_in[4];
    const float* cost1  = (const float*)d_in[5];
    const float* cost2  = (const float*)d_in[6];
    const float* emb1_w = (const float*)d_in[7];
    const float* emb2_w = (const float*)d_in[8];
    float* out = (float*)d_out;

    char* w = (char*)d_ws;
    double* sc  = (double*)w;                       // 8 doubles
    float* tcol = (float*)(w + 256);                // 16 KB (atomic -> zeroed)
    float* trow = (float*)(w + 16640);              // 16 KB
    float* e1   = (float*)(w + 33024);              // 16 KB
    float* e2   = (float*)(w + 49408);              // 16 KB
    float* E1   = (float*)(w + 65792);              // 2 MB
    float* E2   = (float*)(w + 2162944);            // 2 MB
    float* Cw   = (float*)(w + 4260096);            // 64 MB (cost_s then cost_t)
    float* Pw   = (float*)(w + 71368960);           // 64 MB (P = cost_s @ trans)

    // zero scalar accumulators + tcol
    hipMemsetAsync(d_ws, 0, 16640, stream);

    gather_energy<<<N, D, 0, stream>>>(emb1_w, index1, E1, e1);
    gather_energy<<<N, D, 0, stream>>>(emb2_w, index2, E2, e2);
    row_sums<<<N, 256, 0, stream>>>(trans, trow);
    col_sums<<<dim3(16, 32), 256, 0, stream>>>(trans, tcol);

    dim3 g64(N / 64, N / 64);
    dim3 g128(N / 128, N / 128);

    // cost_s -> Cw, + sim1 (sc[0]) and f1-term (sc[1])
    cost_kernel<1><<<g64, 256, 0, stream>>>(E1, E1, e1, e1, cost1, mu_s, trow, Cw, sc);
    // P = cost_s @ trans
    gemm_nn<1><<<g128, 256, 0, stream>>>(Cw, trans, Pw, nullptr, nullptr);
    // cost_t -> Cw (overwrite), + sim2 (sc[0]) and f2-term (sc[1])
    cost_kernel<1><<<g64, 256, 0, stream>>>(E2, E2, e2, e2, cost2, mu_t, tcol, Cw, sc);
    // sc[2] += <trans @ cost_t, P>
    gemm_nn<0><<<g128, 256, 0, stream>>>(trans, Cw, nullptr, Pw, &sc[2]);
    // d_w: fused mutual cost * trans -> sc[3]
    cost_kernel<0><<<g64, 256, 0, stream>>>(E1, E2, e1, e2, trans, nullptr, nullptr, nullptr, sc);
    // orthogonality -> sc[4]
    orth_kernel<<<D, D, 0, stream>>>(E1, sc);
    orth_kernel<<<D, D, 0, stream>>>(E2, sc);

    finalize<<<1, 64, 0, stream>>>(sc, out);
}

// Round 2
// 1351.981 us; speedup vs baseline: 2.6612x; 2.6612x over previous
//
#include <hip/hip_runtime.h>
#include <math.h>

#define N 4096
#define D 128
#define FEPS 1e-5f
#define C0F 0.993262053f

typedef __attribute__((ext_vector_type(8))) short bf16x8;
typedef __attribute__((ext_vector_type(4))) float f32x4;

__device__ __forceinline__ unsigned short f2bf(float f) {
    union { float f; unsigned u; } v; v.f = f;
    unsigned r = v.u + 0x7fffu + ((v.u >> 16) & 1u);
    return (unsigned short)(r >> 16);
}
__device__ __forceinline__ float bf2f(short s) {
    union { unsigned u; float f; } v; v.u = ((unsigned)(unsigned short)s) << 16;
    return v.f;
}

__device__ __forceinline__ void async16(void* lds, const void* g) {
    __builtin_amdgcn_global_load_lds(
        (const __attribute__((address_space(1))) unsigned int*)g,
        (__attribute__((address_space(3))) unsigned int*)lds, 16, 0, 0);
}

// ---------------- reduction helpers ----------------
__device__ __forceinline__ double block_reduce256(double v, double* red) {
    int t = threadIdx.x;
    red[t] = v;
    __syncthreads();
    #pragma unroll
    for (int s = 128; s > 0; s >>= 1) {
        if (t < s) red[t] += red[t + s];
        __syncthreads();
    }
    double r = red[0];
    __syncthreads();
    return r;
}

// ---------------- gather + row norms ----------------
__global__ void gather_energy(const float* __restrict__ W, const int* __restrict__ idx,
                              float* __restrict__ E, float* __restrict__ energy) {
    int i = blockIdx.x, t = threadIdx.x;
    float v = W[(size_t)idx[i] * D + t];
    E[(size_t)i * D + t] = v;
    float sq = v * v;
    #pragma unroll
    for (int o = 32; o > 0; o >>= 1) sq += __shfl_down(sq, o);
    __shared__ float s2[2];
    if ((t & 63) == 0) s2[t >> 6] = sq;
    __syncthreads();
    if (t == 0) energy[i] = sqrtf(s2[0] + s2[1]);
}

// ---------------- trans row sums (+ total sum S into sc[5]) ----------------
__global__ void row_sums(const float* __restrict__ T, float* __restrict__ trow,
                         double* __restrict__ sc) {
    int i = blockIdx.x, t = threadIdx.x;
    float s = 0.f;
    for (int j = t; j < N; j += 256) s += T[(size_t)i * N + j];
    #pragma unroll
    for (int o = 32; o > 0; o >>= 1) s += __shfl_down(s, o);
    __shared__ float sm[4];
    if ((t & 63) == 0) sm[t >> 6] = s;
    __syncthreads();
    if (t == 0) {
        float r = sm[0] + sm[1] + sm[2] + sm[3];
        trow[i] = r;
        atomicAdd(&sc[5], (double)r);
    }
}

// ---------------- trans col sums (tcol must be zeroed) ----------------
__global__ void col_sums(const float* __restrict__ T, float* __restrict__ tcol) {
    int j = blockIdx.x * 256 + threadIdx.x;
    int r0 = blockIdx.y * (N / 32);
    float s = 0.f;
    for (int i = 0; i < N / 32; ++i) s += T[(size_t)(r0 + i) * N + j];
    atomicAdd(&tcol[j], s);
}

// ---------------- trans -> bf16 in A-format (Ta) and B-format (Tb) ----------
// A-fmt slot(r,c) = ((r>>4)*(N/8) + (c>>3))*128 + (r&15)*8 + (c&7), holds M[r][c]
// B-fmt slot for (k,n) = A-fmt slot(n,k), holds M[k][n]
__global__ void trans_convert(const float* __restrict__ T,
                              unsigned short* __restrict__ Ta,
                              unsigned short* __restrict__ Tb) {
    int t = threadIdx.x;
    int cb = blockIdx.x * 64 + (t & 63);   // col-block (4 cols)
    int rb = blockIdx.y * 4 + (t >> 6);    // row-block (4 rows)
    int r0 = rb * 4, c0 = cb * 4;
    float vv[4][4];
    #pragma unroll
    for (int i = 0; i < 4; ++i) {
        float4 r4 = *(const float4*)&T[(size_t)(r0 + i) * N + c0];
        vv[i][0] = r4.x; vv[i][1] = r4.y; vv[i][2] = r4.z; vv[i][3] = r4.w;
    }
    #pragma unroll
    for (int i = 0; i < 4; ++i) {
        int r = r0 + i;
        size_t slot = ((size_t)(r >> 4) * (N / 8) + (c0 >> 3)) * 128 + (r & 15) * 8 + (c0 & 7);
        short4 s;
        s.x = (short)f2bf(vv[i][0]); s.y = (short)f2bf(vv[i][1]);
        s.z = (short)f2bf(vv[i][2]); s.w = (short)f2bf(vv[i][3]);
        *(short4*)&Ta[slot] = s;
    }
    #pragma unroll
    for (int j = 0; j < 4; ++j) {
        int n = c0 + j;
        size_t slot = ((size_t)(n >> 4) * (N / 8) + (r0 >> 3)) * 128 + (n & 15) * 8 + (r0 & 7);
        short4 s;
        s.x = (short)f2bf(vv[0][j]); s.y = (short)f2bf(vv[1][j]);
        s.z = (short)f2bf(vv[2][j]); s.w = (short)f2bf(vv[3][j]);
        *(short4*)&Tb[slot] = s;
    }
}

// ---------------- cosine-cost kernels ----------------
// SELF=1: cost = 1-exp(-5(1-cos)); writes Δ=cost-C0F as bf16 in A-format to outD;
//         sc[0] += (cost-ref)^2*exp(-ref) ; sc[1] += cost^2*mu[col]*tsum[row]
// SELF=0: cost = 1-exp(-(1-cos)); sc[3] += cost*trans[row,col]
template <int SELF>
__global__ __launch_bounds__(256) void cost_kernel(
        const float* __restrict__ EA, const float* __restrict__ EB,
        const float* __restrict__ ea, const float* __restrict__ eb,
        const float* __restrict__ ref_or_trans,
        const float* __restrict__ mu, const float* __restrict__ tsum,
        unsigned short* __restrict__ outD, double* __restrict__ sc) {
    __shared__ float As[16][68];
    __shared__ float Bs[16][68];
    __shared__ double red[256];
    int t = threadIdx.x;
    int tx = t & 15, ty = t >> 4;
    int bi = blockIdx.y * 64, bj = blockIdx.x * 64;
    float acc[4][4] = {};
    for (int kk = 0; kk < D; kk += 16) {
        #pragma unroll
        for (int r = 0; r < 4; ++r) {
            int e = t + 256 * r;
            int ar = e >> 4, ac = e & 15;
            As[ac][ar] = EA[(size_t)(bi + ar) * D + kk + ac];
            Bs[ac][ar] = EB[(size_t)(bj + ar) * D + kk + ac];
        }
        __syncthreads();
        #pragma unroll
        for (int k = 0; k < 16; ++k) {
            float4 av = *(const float4*)&As[k][ty * 4];
            float4 bv = *(const float4*)&Bs[k][tx * 4];
            float a[4] = {av.x, av.y, av.z, av.w};
            float b[4] = {bv.x, bv.y, bv.z, bv.w};
            #pragma unroll
            for (int u = 0; u < 4; ++u)
                #pragma unroll
                for (int v = 0; v < 4; ++v)
                    acc[u][v] = fmaf(a[u], b[v], acc[u][v]);
        }
        __syncthreads();
    }
    float eav[4], ebv[4];
    #pragma unroll
    for (int u = 0; u < 4; ++u) eav[u] = ea[bi + ty * 4 + u];
    #pragma unroll
    for (int v = 0; v < 4; ++v) ebv[v] = eb[bj + tx * 4 + v];

    double l1 = 0.0, l2 = 0.0;
    #pragma unroll
    for (int u = 0; u < 4; ++u) {
        int ri = bi + ty * 4 + u;
        float cv[4];
        #pragma unroll
        for (int v = 0; v < 4; ++v) {
            int ci = bj + tx * 4 + v;
            size_t id = (size_t)ri * N + ci;
            float denom = eav[u] * ebv[v] + FEPS;
            float cosv = acc[u][v] / denom;
            if (SELF) {
                float c = 1.f - expf(-5.f * (1.f - cosv));
                cv[v] = c;
                float rc = ref_or_trans[id];
                float dd = c - rc;
                l1 += (double)(dd * dd * expf(-rc));
                l2 += (double)(c * c) * (double)mu[ci] * (double)tsum[ri];
            } else {
                float c = 1.f - expf(-(1.f - cosv));
                l1 += (double)c * (double)ref_or_trans[id];
            }
        }
        if (SELF) {
            int ci0 = bj + tx * 4;
            size_t slot = ((size_t)(ri >> 4) * (N / 8) + (ci0 >> 3)) * 128 + (ri & 15) * 8 + (ci0 & 7);
            short4 s;
            s.x = (short)f2bf(cv[0] - C0F); s.y = (short)f2bf(cv[1] - C0F);
            s.z = (short)f2bf(cv[2] - C0F); s.w = (short)f2bf(cv[3] - C0F);
            *(short4*)&outD[slot] = s;
        }
    }
    double s1 = block_reduce256(l1, red);
    if (SELF) {
        double s2v = block_reduce256(l2, red);
        if (t == 0) { atomicAdd(&sc[0], s1); atomicAdd(&sc[1], s2v); }
    } else {
        if (t == 0) atomicAdd(&sc[3], s1);
    }
}

// ---------------- bf16 MFMA GEMM, 128x128 tile, 16x16x32, m97 structure -----
// STORE=1: Pd = A@B -> Pdb (bf16, C-fragment-native tiled layout)
// STORE=0: Qd = A@B; epilogue: sc[6]+=Σ tcol[j]*Qd, sc[7]+=Σ trow[i]*Pd,
//          sc[2]+=Σ Pd*Qd   (Pd read back from Pdb, same slot geometry)
template <int STORE>
__global__ __launch_bounds__(256) void gemm_mfma(
        const unsigned short* __restrict__ Ag, const unsigned short* __restrict__ Bg,
        unsigned short* __restrict__ Pdb,
        const float* __restrict__ trow, const float* __restrict__ tcol,
        double* __restrict__ sc) {
    __shared__ __align__(16) char As[8192];
    __shared__ __align__(16) char Bs[8192];
    __shared__ double red[256];
    const int t = threadIdx.x, w = t >> 6, l = t & 63;
    const int wm = w >> 1, wn = w & 1;
    const int bx = blockIdx.x, by = blockIdx.y;
    const size_t grp = (size_t)(N / 8) * 256;  // bytes per row-group (all k-chunks)

    const char* aP0 = (const char*)Ag + (size_t)(by * 8 + w * 2) * grp + l * 16;
    const char* aP1 = aP0 + grp;
    const char* bP0 = (const char*)Bg + (size_t)(bx * 8 + w * 2) * grp + l * 16;
    const char* bP1 = bP0 + grp;
    char* AsD0 = As + (w * 2 + 0) * 1024;
    char* AsD1 = As + (w * 2 + 1) * 1024;
    char* BsD0 = Bs + (w * 2 + 0) * 1024;
    char* BsD1 = Bs + (w * 2 + 1) * 1024;
    const char* ArdA = As + (wm * 4) * 1024 + l * 16;
    const char* BrdB = Bs + (wn * 4) * 1024 + l * 16;

    f32x4 acc[4][4];
    #pragma unroll
    for (int i = 0; i < 4; ++i)
        #pragma unroll
        for (int j = 0; j < 4; ++j)
            acc[i][j] = (f32x4){0.f, 0.f, 0.f, 0.f};

    for (int it = 0; it < N / 32; ++it) {
        async16(AsD0, aP0); async16(AsD1, aP1);
        async16(BsD0, bP0); async16(BsD1, bP1);
        aP0 += 1024; aP1 += 1024; bP0 += 1024; bP1 += 1024;
        __syncthreads();
        bf16x8 af[4], bfr[4];
        #pragma unroll
        for (int f = 0; f < 4; ++f) {
            af[f]  = *(const bf16x8*)(ArdA + f * 1024);
            bfr[f] = *(const bf16x8*)(BrdB + f * 1024);
        }
        #pragma unroll
        for (int mf = 0; mf < 4; ++mf)
            #pragma unroll
            for (int nf = 0; nf < 4; ++nf)
                acc[mf][nf] = __builtin_amdgcn_mfma_f32_16x16x32_bf16(
                    af[mf], bfr[nf], acc[mf][nf], 0, 0, 0);
        __syncthreads();
    }

    const size_t blkbase = (size_t)(by * 32 + bx) * 4096 + (size_t)w * 1024;
    if (STORE) {
        #pragma unroll
        for (int mf = 0; mf < 4; ++mf)
            #pragma unroll
            for (int nf = 0; nf < 4; ++nf) {
                f32x4 a = acc[mf][nf];
                short4 s;
                s.x = (short)f2bf(a[0]); s.y = (short)f2bf(a[1]);
                s.z = (short)f2bf(a[2]); s.w = (short)f2bf(a[3]);
                *(short4*)&Pdb[(blkbase + (mf * 4 + nf) * 64 + l) * 4] = s;
            }
    } else {
        double t1 = 0.0, t2 = 0.0, t3 = 0.0;
        const int quad = l >> 4, lan = l & 15;
        #pragma unroll
        for (int mf = 0; mf < 4; ++mf) {
            const int ib = by * 128 + wm * 64 + mf * 16 + quad * 4;  // row i base
            float4 tr4 = *(const float4*)&trow[ib];
            float trv[4] = {tr4.x, tr4.y, tr4.z, tr4.w};
            #pragma unroll
            for (int nf = 0; nf < 4; ++nf) {
                const int j = bx * 128 + wn * 64 + nf * 16 + lan;    // col j
                const float tcj = tcol[j];
                short4 p = *(const short4*)&Pdb[(blkbase + (mf * 4 + nf) * 64 + l) * 4];
                float pf[4] = {bf2f(p.x), bf2f(p.y), bf2f(p.z), bf2f(p.w)};
                #pragma unroll
                for (int r = 0; r < 4; ++r) {
                    double x = (double)acc[mf][nf][r];
                    t1 += (double)tcj * x;
                    t2 += (double)trv[r] * (double)pf[r];
                    t3 += x * (double)pf[r];
                }
            }
        }
        double s1 = block_reduce256(t1, red);
        double s2 = block_reduce256(t2, red);
        double s3 = block_reduce256(t3, red);
        if (t == 0) {
            atomicAdd(&sc[6], s1);
            atomicAdd(&sc[7], s2);
            atomicAdd(&sc[2], s3);
        }
    }
}

// ---------------- orthogonality: sum((E^T E - I)^2) ----------------
__global__ void orth_kernel(const float* __restrict__ E, double* __restrict__ sc) {
    int a = blockIdx.x, b = threadIdx.x;
    float acc = 0.f;
    for (int i = 0; i < N; ++i)
        acc = fmaf(E[(size_t)i * D + a], E[(size_t)i * D + b], acc);
    if (a == b) acc -= 1.f;
    double v = (double)acc * (double)acc;
    #pragma unroll
    for (int o = 32; o > 0; o >>= 1) v += __shfl_down(v, o);
    __shared__ double sm[2];
    if ((b & 63) == 0) sm[b >> 6] = v;
    __syncthreads();
    if (b == 0) atomicAdd(&sc[4], sm[0] + sm[1]);
}

// ---------------- finalize ----------------
__global__ void finalize(const double* __restrict__ sc, float* __restrict__ out) {
    if (threadIdx.x == 0) {
        const double C0 = (double)C0F;
        double S = sc[5];
        double pq = C0 * C0 * S * S + C0 * sc[6] + C0 * sc[7] + sc[2];
        out[0] = (float)(sc[1] - 2.0 * pq);  // d_gw
        out[1] = (float)sc[3];               // d_w
        out[2] = (float)(sc[0] + sc[4]);     // regularizer
    }
}

extern "C" void kernel_launch(void* const* d_in, const int* in_sizes, int n_in,
                              void* d_out, int out_size, void* d_ws, size_t ws_size,
                              hipStream_t stream) {
    const int*   index1 = (const int*)d_in[0];
    const int*   index2 = (const int*)d_in[1];
    const float* trans  = (const float*)d_in[2];
    const float* mu_s   = (const float*)d_in[3];
    const float* mu_t   = (const float*)d_in[4];
    const float* cost1  = (const float*)d_in[5];
    const float* cost2  = (const float*)d_in[6];
    const float* emb1_w = (const float*)d_in[7];
    const float* emb2_w = (const float*)d_in[8];
    float* out = (float*)d_out;

    char* w = (char*)d_ws;
    double* sc  = (double*)w;                          // 8 doubles @0
    float* tcol = (float*)(w + 256);                   // 16 KB (zeroed)
    float* trow = (float*)(w + 16640);                 // 16 KB
    float* e1   = (float*)(w + 33024);                 // 16 KB
    float* e2   = (float*)(w + 49408);                 // 16 KB
    float* E1   = (float*)(w + 65792);                 // 2 MB
    float* E2   = (float*)(w + 2162944);               // 2 MB
    unsigned short* Ds  = (unsigned short*)(w + 4260096);    // 32 MB (Δs, then Δt)
    unsigned short* Ta  = (unsigned short*)(w + 37814528);   // 32 MB trans A-fmt
    unsigned short* Tb  = (unsigned short*)(w + 71368960);   // 32 MB trans B-fmt
    unsigned short* Pdb = (unsigned short*)(w + 104923392);  // 32 MB Pd bf16 (C-layout)

    hipMemsetAsync(d_ws, 0, 16640, stream);  // sc + tcol

    gather_energy<<<N, D, 0, stream>>>(emb1_w, index1, E1, e1);
    gather_energy<<<N, D, 0, stream>>>(emb2_w, index2, E2, e2);
    row_sums<<<N, 256, 0, stream>>>(trans, trow, sc);
    col_sums<<<dim3(16, 32), 256, 0, stream>>>(trans, tcol);
    trans_convert<<<dim3(16, 256), 256, 0, stream>>>(trans, Ta, Tb);

    dim3 g64(N / 64, N / 64);
    dim3 g32(N / 128, N / 128);

    // Δs (+ sim1 -> sc[0], f1-term -> sc[1])
    cost_kernel<1><<<g64, 256, 0, stream>>>(E1, E1, e1, e1, cost1, mu_s, trow, Ds, sc);
    // Pd = Δs @ trans  (A = Δs A-fmt, B = trans B-fmt)
    gemm_mfma<1><<<g32, 256, 0, stream>>>(Ds, Tb, Pdb, nullptr, nullptr, sc);
    // Δt (+ sim2 -> sc[0], f2-term -> sc[1]); reuses Ds buffer (Δs dead)
    cost_kernel<1><<<g64, 256, 0, stream>>>(E2, E2, e2, e2, cost2, mu_t, tcol, Ds, sc);
    // Qd = trans @ Δt (A = trans A-fmt, B = Δt symmetric A-fmt); fused epilogue
    gemm_mfma<0><<<g32, 256, 0, stream>>>(Ta, Ds, Pdb, trow, tcol, sc);
    // d_w -> sc[3]
    cost_kernel<0><<<g64, 256, 0, stream>>>(E1, E2, e1, e2, trans, nullptr, nullptr, nullptr, sc);
    // orthogonality -> sc[4]
    orth_kernel<<<D, D, 0, stream>>>(E1, sc);
    orth_kernel<<<D, D, 0, stream>>>(E2, sc);

    finalize<<<1, 64, 0, stream>>>(sc, out);
}

// Round 3
// 1225.154 us; speedup vs baseline: 2.9367x; 1.1035x over previous
//
#include <hip/hip_runtime.h>
#include <math.h>

#define N 4096
#define D 128
#define FEPS 1e-5f
#define C0F 0.993262053f

typedef __attribute__((ext_vector_type(8))) short bf16x8;
typedef __attribute__((ext_vector_type(4))) float f32x4;

__device__ __forceinline__ unsigned short f2bf(float f) {
    union { float f; unsigned u; } v; v.f = f;
    unsigned r = v.u + 0x7fffu + ((v.u >> 16) & 1u);
    return (unsigned short)(r >> 16);
}
__device__ __forceinline__ float bf2f(short s) {
    union { unsigned u; float f; } v; v.u = ((unsigned)(unsigned short)s) << 16;
    return v.f;
}

__device__ __forceinline__ void async16(void* lds, const void* g) {
    __builtin_amdgcn_global_load_lds(
        (const __attribute__((address_space(1))) unsigned int*)g,
        (__attribute__((address_space(3))) unsigned int*)lds, 16, 0, 0);
}

// ---------------- reduction helpers ----------------
__device__ __forceinline__ double block_reduce256(double v, double* red) {
    int t = threadIdx.x;
    red[t] = v;
    __syncthreads();
    #pragma unroll
    for (int s = 128; s > 0; s >>= 1) {
        if (t < s) red[t] += red[t + s];
        __syncthreads();
    }
    double r = red[0];
    __syncthreads();
    return r;
}

// ---------------- gather + row norms ----------------
__global__ void gather_energy(const float* __restrict__ W, const int* __restrict__ idx,
                              float* __restrict__ E, float* __restrict__ energy) {
    int i = blockIdx.x, t = threadIdx.x;
    float v = W[(size_t)idx[i] * D + t];
    E[(size_t)i * D + t] = v;
    float sq = v * v;
    #pragma unroll
    for (int o = 32; o > 0; o >>= 1) sq += __shfl_down(sq, o);
    __shared__ float s2[2];
    if ((t & 63) == 0) s2[t >> 6] = sq;
    __syncthreads();
    if (t == 0) energy[i] = sqrtf(s2[0] + s2[1]);
}

// ---------------- trans row sums (+ total sum S into sc[5]) ----------------
__global__ void row_sums(const float* __restrict__ T, float* __restrict__ trow,
                         double* __restrict__ sc) {
    int i = blockIdx.x, t = threadIdx.x;
    float s = 0.f;
    for (int j = t; j < N; j += 256) s += T[(size_t)i * N + j];
    #pragma unroll
    for (int o = 32; o > 0; o >>= 1) s += __shfl_down(s, o);
    __shared__ float sm[4];
    if ((t & 63) == 0) sm[t >> 6] = s;
    __syncthreads();
    if (t == 0) {
        float r = sm[0] + sm[1] + sm[2] + sm[3];
        trow[i] = r;
        atomicAdd(&sc[5], (double)r);
    }
}

// ---------------- trans col sums (tcol must be zeroed) ----------------
__global__ void col_sums(const float* __restrict__ T, float* __restrict__ tcol) {
    int j = blockIdx.x * 256 + threadIdx.x;
    int r0 = blockIdx.y * (N / 32);
    float s = 0.f;
    for (int i = 0; i < N / 32; ++i) s += T[(size_t)(r0 + i) * N + j];
    atomicAdd(&tcol[j], s);
}

// ---------------- trans -> bf16 in A-format (Ta) and B-format (Tb) ----------
// A-fmt slot(r,c) = ((r>>4)*(N/8) + (c>>3))*128 + (r&15)*8 + (c&7), holds M[r][c]
// B-fmt slot for (k,n) = A-fmt slot(n,k), holds M[k][n]
__global__ void trans_convert(const float* __restrict__ T,
                              unsigned short* __restrict__ Ta,
                              unsigned short* __restrict__ Tb) {
    int t = threadIdx.x;
    int cb = blockIdx.x * 64 + (t & 63);   // col-block (4 cols)
    int rb = blockIdx.y * 4 + (t >> 6);    // row-block (4 rows)
    int r0 = rb * 4, c0 = cb * 4;
    float vv[4][4];
    #pragma unroll
    for (int i = 0; i < 4; ++i) {
        float4 r4 = *(const float4*)&T[(size_t)(r0 + i) * N + c0];
        vv[i][0] = r4.x; vv[i][1] = r4.y; vv[i][2] = r4.z; vv[i][3] = r4.w;
    }
    #pragma unroll
    for (int i = 0; i < 4; ++i) {
        int r = r0 + i;
        size_t slot = ((size_t)(r >> 4) * (N / 8) + (c0 >> 3)) * 128 + (r & 15) * 8 + (c0 & 7);
        short4 s;
        s.x = (short)f2bf(vv[i][0]); s.y = (short)f2bf(vv[i][1]);
        s.z = (short)f2bf(vv[i][2]); s.w = (short)f2bf(vv[i][3]);
        *(short4*)&Ta[slot] = s;
    }
    #pragma unroll
    for (int j = 0; j < 4; ++j) {
        int n = c0 + j;
        size_t slot = ((size_t)(n >> 4) * (N / 8) + (r0 >> 3)) * 128 + (n & 15) * 8 + (r0 & 7);
        short4 s;
        s.x = (short)f2bf(vv[0][j]); s.y = (short)f2bf(vv[1][j]);
        s.z = (short)f2bf(vv[2][j]); s.w = (short)f2bf(vv[3][j]);
        *(short4*)&Tb[slot] = s;
    }
}

// ---------------- cosine-cost kernels ----------------
template <int SELF>
__global__ __launch_bounds__(256) void cost_kernel(
        const float* __restrict__ EA, const float* __restrict__ EB,
        const float* __restrict__ ea, const float* __restrict__ eb,
        const float* __restrict__ ref_or_trans,
        const float* __restrict__ mu, const float* __restrict__ tsum,
        unsigned short* __restrict__ outD, double* __restrict__ sc) {
    __shared__ float As[16][68];
    __shared__ float Bs[16][68];
    __shared__ double red[256];
    int t = threadIdx.x;
    int tx = t & 15, ty = t >> 4;
    int bi = blockIdx.y * 64, bj = blockIdx.x * 64;
    float acc[4][4] = {};
    for (int kk = 0; kk < D; kk += 16) {
        #pragma unroll
        for (int r = 0; r < 4; ++r) {
            int e = t + 256 * r;
            int ar = e >> 4, ac = e & 15;
            As[ac][ar] = EA[(size_t)(bi + ar) * D + kk + ac];
            Bs[ac][ar] = EB[(size_t)(bj + ar) * D + kk + ac];
        }
        __syncthreads();
        #pragma unroll
        for (int k = 0; k < 16; ++k) {
            float4 av = *(const float4*)&As[k][ty * 4];
            float4 bv = *(const float4*)&Bs[k][tx * 4];
            float a[4] = {av.x, av.y, av.z, av.w};
            float b[4] = {bv.x, bv.y, bv.z, bv.w};
            #pragma unroll
            for (int u = 0; u < 4; ++u)
                #pragma unroll
                for (int v = 0; v < 4; ++v)
                    acc[u][v] = fmaf(a[u], b[v], acc[u][v]);
        }
        __syncthreads();
    }
    float eav[4], ebv[4];
    #pragma unroll
    for (int u = 0; u < 4; ++u) eav[u] = ea[bi + ty * 4 + u];
    #pragma unroll
    for (int v = 0; v < 4; ++v) ebv[v] = eb[bj + tx * 4 + v];

    double l1 = 0.0, l2 = 0.0;
    #pragma unroll
    for (int u = 0; u < 4; ++u) {
        int ri = bi + ty * 4 + u;
        float cv[4];
        #pragma unroll
        for (int v = 0; v < 4; ++v) {
            int ci = bj + tx * 4 + v;
            size_t id = (size_t)ri * N + ci;
            float denom = eav[u] * ebv[v] + FEPS;
            float cosv = acc[u][v] / denom;
            if (SELF) {
                float c = 1.f - expf(-5.f * (1.f - cosv));
                cv[v] = c;
                float rc = ref_or_trans[id];
                float dd = c - rc;
                l1 += (double)(dd * dd * expf(-rc));
                l2 += (double)(c * c) * (double)mu[ci] * (double)tsum[ri];
            } else {
                float c = 1.f - expf(-(1.f - cosv));
                l1 += (double)c * (double)ref_or_trans[id];
            }
        }
        if (SELF) {
            int ci0 = bj + tx * 4;
            size_t slot = ((size_t)(ri >> 4) * (N / 8) + (ci0 >> 3)) * 128 + (ri & 15) * 8 + (ci0 & 7);
            short4 s;
            s.x = (short)f2bf(cv[0] - C0F); s.y = (short)f2bf(cv[1] - C0F);
            s.z = (short)f2bf(cv[2] - C0F); s.w = (short)f2bf(cv[3] - C0F);
            *(short4*)&outD[slot] = s;
        }
    }
    double s1 = block_reduce256(l1, red);
    if (SELF) {
        double s2v = block_reduce256(l2, red);
        if (t == 0) { atomicAdd(&sc[0], s1); atomicAdd(&sc[1], s2v); }
    } else {
        if (t == 0) atomicAdd(&sc[3], s1);
    }
}

// ---------------- bf16 MFMA GEMM, 128x128 tile, double-buffered prefetch ----
__device__ __forceinline__ void mfma_step(const char* ard, const char* brd,
                                          f32x4 (&acc)[4][4]) {
    bf16x8 af[4], bfr[4];
    #pragma unroll
    for (int f = 0; f < 4; ++f) {
        af[f]  = *(const bf16x8*)(ard + f * 1024);
        bfr[f] = *(const bf16x8*)(brd + f * 1024);
    }
    #pragma unroll
    for (int mf = 0; mf < 4; ++mf)
        #pragma unroll
        for (int nf = 0; nf < 4; ++nf)
            acc[mf][nf] = __builtin_amdgcn_mfma_f32_16x16x32_bf16(
                af[mf], bfr[nf], acc[mf][nf], 0, 0, 0);
}

// STORE=1: Pd = A@B -> Pdb (bf16, C-fragment-native tiled layout)
// STORE=0: Qd = A@B; epilogue: sc[6]+=Σ tcol[j]*Qd, sc[7]+=Σ trow[i]*Pd,
//          sc[2]+=Σ Pd*Qd
template <int STORE>
__global__ __launch_bounds__(256) void gemm_mfma(
        const unsigned short* __restrict__ Ag, const unsigned short* __restrict__ Bg,
        unsigned short* __restrict__ Pdb,
        const float* __restrict__ trow, const float* __restrict__ tcol,
        double* __restrict__ sc) {
    __shared__ __align__(16) char As0[8192], As1[8192];
    __shared__ __align__(16) char Bs0[8192], Bs1[8192];
    __shared__ double red[256];
    const int t = threadIdx.x, w = t >> 6, l = t & 63;
    const int wm = w >> 1, wn = w & 1;
    const int bx = blockIdx.x, by = blockIdx.y;
    const size_t grp = (size_t)(N / 8) * 256;  // bytes per 16-row group (all k)

    const char* aP0 = (const char*)Ag + (size_t)(by * 8 + w * 2) * grp + l * 16;
    const char* aP1 = aP0 + grp;
    const char* bP0 = (const char*)Bg + (size_t)(bx * 8 + w * 2) * grp + l * 16;
    const char* bP1 = bP0 + grp;

    char* a0d0 = As0 + (w * 2 + 0) * 1024; char* a0d1 = As0 + (w * 2 + 1) * 1024;
    char* a1d0 = As1 + (w * 2 + 0) * 1024; char* a1d1 = As1 + (w * 2 + 1) * 1024;
    char* b0d0 = Bs0 + (w * 2 + 0) * 1024; char* b0d1 = Bs0 + (w * 2 + 1) * 1024;
    char* b1d0 = Bs1 + (w * 2 + 0) * 1024; char* b1d1 = Bs1 + (w * 2 + 1) * 1024;

    const char* ard0 = As0 + (wm * 4) * 1024 + l * 16;
    const char* brd0 = Bs0 + (wn * 4) * 1024 + l * 16;
    const char* ard1 = As1 + (wm * 4) * 1024 + l * 16;
    const char* brd1 = Bs1 + (wn * 4) * 1024 + l * 16;

    f32x4 acc[4][4];
    #pragma unroll
    for (int i = 0; i < 4; ++i)
        #pragma unroll
        for (int j = 0; j < 4; ++j)
            acc[i][j] = (f32x4){0.f, 0.f, 0.f, 0.f};

    // preload chunk 0 -> buf0
    async16(a0d0, aP0); async16(a0d1, aP1);
    async16(b0d0, bP0); async16(b0d1, bP1);
    aP0 += 1024; aP1 += 1024; bP0 += 1024; bP1 += 1024;

    for (int it = 0; it < N / 32; it += 2) {
        __syncthreads();               // drains chunk it (issued one phase ago)
        // prefetch chunk it+1 -> buf1 (it <= 126 so always valid)
        async16(a1d0, aP0); async16(a1d1, aP1);
        async16(b1d0, bP0); async16(b1d1, bP1);
        aP0 += 1024; aP1 += 1024; bP0 += 1024; bP1 += 1024;
        mfma_step(ard0, brd0, acc);    // consume buf0
        __syncthreads();               // drains chunk it+1
        if (it < N / 32 - 2) {
            // prefetch chunk it+2 -> buf0
            async16(a0d0, aP0); async16(a0d1, aP1);
            async16(b0d0, bP0); async16(b0d1, bP1);
            aP0 += 1024; aP1 += 1024; bP0 += 1024; bP1 += 1024;
        }
        mfma_step(ard1, brd1, acc);    // consume buf1
    }

    const size_t blkbase = (size_t)(by * 32 + bx) * 4096 + (size_t)w * 1024;
    if (STORE) {
        #pragma unroll
        for (int mf = 0; mf < 4; ++mf)
            #pragma unroll
            for (int nf = 0; nf < 4; ++nf) {
                f32x4 a = acc[mf][nf];
                short4 s;
                s.x = (short)f2bf(a[0]); s.y = (short)f2bf(a[1]);
                s.z = (short)f2bf(a[2]); s.w = (short)f2bf(a[3]);
                *(short4*)&Pdb[(blkbase + (mf * 4 + nf) * 64 + l) * 4] = s;
            }
    } else {
        double t1 = 0.0, t2 = 0.0, t3 = 0.0;
        const int quad = l >> 4, lan = l & 15;
        #pragma unroll
        for (int mf = 0; mf < 4; ++mf) {
            const int ib = by * 128 + wm * 64 + mf * 16 + quad * 4;  // row i base
            float4 tr4 = *(const float4*)&trow[ib];
            float trv[4] = {tr4.x, tr4.y, tr4.z, tr4.w};
            #pragma unroll
            for (int nf = 0; nf < 4; ++nf) {
                const int j = bx * 128 + wn * 64 + nf * 16 + lan;    // col j
                const float tcj = tcol[j];
                short4 p = *(const short4*)&Pdb[(blkbase + (mf * 4 + nf) * 64 + l) * 4];
                float pf[4] = {bf2f(p.x), bf2f(p.y), bf2f(p.z), bf2f(p.w)};
                #pragma unroll
                for (int r = 0; r < 4; ++r) {
                    double x = (double)acc[mf][nf][r];
                    t1 += (double)tcj * x;
                    t2 += (double)trv[r] * (double)pf[r];
                    t3 += x * (double)pf[r];
                }
            }
        }
        double s1 = block_reduce256(t1, red);
        double s2 = block_reduce256(t2, red);
        double s3 = block_reduce256(t3, red);
        if (t == 0) {
            atomicAdd(&sc[6], s1);
            atomicAdd(&sc[7], s2);
            atomicAdd(&sc[2], s3);
        }
    }
}

// ---------------- orthogonality: tiled gram partials + finalize -------------
// G (D*D floats, zeroed) accumulates E^T E via atomics; 32 blocks of 128 rows.
__global__ __launch_bounds__(256) void gram_partial(const float* __restrict__ E,
                                                    float* __restrict__ G) {
    __shared__ float Es[16][132];
    int t = threadIdx.x, tx = t & 15, ty = t >> 4;
    int i0 = blockIdx.x * 128;
    float acc[8][8] = {};
    for (int kk = 0; kk < 128; kk += 16) {
        #pragma unroll
        for (int r = 0; r < 2; ++r) {
            int q = t + 256 * r;
            int row = q >> 5, c4 = (q & 31) * 4;
            *(float4*)&Es[row][c4] = *(const float4*)&E[(size_t)(i0 + kk + row) * D + c4];
        }
        __syncthreads();
        #pragma unroll
        for (int k = 0; k < 16; ++k) {
            float a[8], b[8];
            *(float4*)&a[0] = *(const float4*)&Es[k][ty * 8];
            *(float4*)&a[4] = *(const float4*)&Es[k][ty * 8 + 4];
            *(float4*)&b[0] = *(const float4*)&Es[k][tx * 8];
            *(float4*)&b[4] = *(const float4*)&Es[k][tx * 8 + 4];
            #pragma unroll
            for (int u = 0; u < 8; ++u)
                #pragma unroll
                for (int v = 0; v < 8; ++v)
                    acc[u][v] = fmaf(a[u], b[v], acc[u][v]);
        }
        __syncthreads();
    }
    #pragma unroll
    for (int u = 0; u < 8; ++u)
        #pragma unroll
        for (int v = 0; v < 8; ++v)
            atomicAdd(&G[(size_t)(ty * 8 + u) * D + tx * 8 + v], acc[u][v]);
}

// grid 2 blocks: block b handles G + b*D*D; sum((G - I)^2) -> sc[4]
__global__ void orth_final(const float* __restrict__ G, double* __restrict__ sc) {
    __shared__ double red[256];
    const float* g = G + (size_t)blockIdx.x * D * D;
    int t = threadIdx.x;
    double s = 0.0;
    for (int q = t; q < D * D; q += 256) {
        float v = g[q] - ((q % (D + 1)) == 0 ? 1.f : 0.f);
        s += (double)v * (double)v;
    }
    double r = block_reduce256(s, red);
    if (t == 0) atomicAdd(&sc[4], r);
}

// ---------------- finalize ----------------
__global__ void finalize(const double* __restrict__ sc, float* __restrict__ out) {
    if (threadIdx.x == 0) {
        const double C0 = (double)C0F;
        double S = sc[5];
        double pq = C0 * C0 * S * S + C0 * sc[6] + C0 * sc[7] + sc[2];
        out[0] = (float)(sc[1] - 2.0 * pq);  // d_gw
        out[1] = (float)sc[3];               // d_w
        out[2] = (float)(sc[0] + sc[4]);     // regularizer
    }
}

extern "C" void kernel_launch(void* const* d_in, const int* in_sizes, int n_in,
                              void* d_out, int out_size, void* d_ws, size_t ws_size,
                              hipStream_t stream) {
    const int*   index1 = (const int*)d_in[0];
    const int*   index2 = (const int*)d_in[1];
    const float* trans  = (const float*)d_in[2];
    const float* mu_s   = (const float*)d_in[3];
    const float* mu_t   = (const float*)d_in[4];
    const float* cost1  = (const float*)d_in[5];
    const float* cost2  = (const float*)d_in[6];
    const float* emb1_w = (const float*)d_in[7];
    const float* emb2_w = (const float*)d_in[8];
    float* out = (float*)d_out;

    char* w = (char*)d_ws;
    double* sc  = (double*)w;                          // 8 doubles @0
    float* tcol = (float*)(w + 256);                   // 16 KB (zeroed)
    float* trow = (float*)(w + 16640);                 // 16 KB
    float* e1   = (float*)(w + 33024);                 // 16 KB
    float* e2   = (float*)(w + 49408);                 // 16 KB
    float* E1   = (float*)(w + 65792);                 // 2 MB
    float* E2   = (float*)(w + 2162944);               // 2 MB
    unsigned short* Ds  = (unsigned short*)(w + 4260096);    // 32 MB (Δs, then Δt)
    unsigned short* Ta  = (unsigned short*)(w + 37814528);   // 32 MB trans A-fmt
    unsigned short* Tb  = (unsigned short*)(w + 71368960);   // 32 MB trans B-fmt
    unsigned short* Pdb = (unsigned short*)(w + 104923392);  // 32 MB Pd bf16 (C-layout)
    float* Gbuf = (float*)(w + 37814528);              // 128 KB, overlays Ta (dead after gemm2)

    hipMemsetAsync(d_ws, 0, 16640, stream);  // sc + tcol

    gather_energy<<<N, D, 0, stream>>>(emb1_w, index1, E1, e1);
    gather_energy<<<N, D, 0, stream>>>(emb2_w, index2, E2, e2);
    row_sums<<<N, 256, 0, stream>>>(trans, trow, sc);
    col_sums<<<dim3(16, 32), 256, 0, stream>>>(trans, tcol);
    trans_convert<<<dim3(16, 256), 256, 0, stream>>>(trans, Ta, Tb);

    dim3 g64(N / 64, N / 64);
    dim3 g32(N / 128, N / 128);

    // Δs (+ sim1 -> sc[0], f1-term -> sc[1])
    cost_kernel<1><<<g64, 256, 0, stream>>>(E1, E1, e1, e1, cost1, mu_s, trow, Ds, sc);
    // Pd = Δs @ trans
    gemm_mfma<1><<<g32, 256, 0, stream>>>(Ds, Tb, Pdb, nullptr, nullptr, sc);
    // Δt (+ sim2 -> sc[0], f2-term -> sc[1]); reuses Ds
    cost_kernel<1><<<g64, 256, 0, stream>>>(E2, E2, e2, e2, cost2, mu_t, tcol, Ds, sc);
    // Qd = trans @ Δt; fused epilogue (sc[2], sc[6], sc[7])
    gemm_mfma<0><<<g32, 256, 0, stream>>>(Ta, Ds, Pdb, trow, tcol, sc);
    // d_w -> sc[3]
    cost_kernel<0><<<g64, 256, 0, stream>>>(E1, E2, e1, e2, trans, nullptr, nullptr, nullptr, sc);
    // orthogonality: G = E^T E (Gbuf overlays Ta, now dead), then sum((G-I)^2)
    hipMemsetAsync(Gbuf, 0, 2 * D * D * sizeof(float), stream);
    gram_partial<<<32, 256, 0, stream>>>(E1, Gbuf);
    gram_partial<<<32, 256, 0, stream>>>(E2, Gbuf + D * D);
    orth_final<<<2, 256, 0, stream>>>(Gbuf, sc);

    finalize<<<1, 64, 0, stream>>>(sc, out);
}

// Round 4
// 1086.015 us; speedup vs baseline: 3.3129x; 1.1281x over previous
//
#include <hip/hip_runtime.h>
#include <math.h>

#define N 4096
#define D 128
#define FEPS 1e-5f
#define C0F 0.993262053f

typedef __attribute__((ext_vector_type(8))) short bf16x8;
typedef __attribute__((ext_vector_type(4))) float f32x4;

__device__ __forceinline__ unsigned short f2bf(float f) {
    union { float f; unsigned u; } v; v.f = f;
    unsigned r = v.u + 0x7fffu + ((v.u >> 16) & 1u);
    return (unsigned short)(r >> 16);
}
__device__ __forceinline__ float bf2f(short s) {
    union { unsigned u; float f; } v; v.u = ((unsigned)(unsigned short)s) << 16;
    return v.f;
}

__device__ __forceinline__ void async16(void* lds, const void* g) {
    __builtin_amdgcn_global_load_lds(
        (const __attribute__((address_space(1))) unsigned int*)g,
        (__attribute__((address_space(3))) unsigned int*)lds, 16, 0, 0);
}

// ---------------- reduction helpers ----------------
__device__ __forceinline__ double block_reduce256(double v, double* red) {
    int t = threadIdx.x;
    red[t] = v;
    __syncthreads();
    #pragma unroll
    for (int s = 128; s > 0; s >>= 1) {
        if (t < s) red[t] += red[t + s];
        __syncthreads();
    }
    double r = red[0];
    __syncthreads();
    return r;
}

// ---------------- gather + row norms ----------------
__global__ void gather_energy(const float* __restrict__ W, const int* __restrict__ idx,
                              float* __restrict__ E, float* __restrict__ energy) {
    int i = blockIdx.x, t = threadIdx.x;
    float v = W[(size_t)idx[i] * D + t];
    E[(size_t)i * D + t] = v;
    float sq = v * v;
    #pragma unroll
    for (int o = 32; o > 0; o >>= 1) sq += __shfl_down(sq, o);
    __shared__ float s2[2];
    if ((t & 63) == 0) s2[t >> 6] = sq;
    __syncthreads();
    if (t == 0) energy[i] = sqrtf(s2[0] + s2[1]);
}

// ---------------- trans row sums (+ total sum S into sc[5]) ----------------
__global__ void row_sums(const float* __restrict__ T, float* __restrict__ trow,
                         double* __restrict__ sc) {
    int i = blockIdx.x, t = threadIdx.x;
    float s = 0.f;
    for (int j = t; j < N; j += 256) s += T[(size_t)i * N + j];
    #pragma unroll
    for (int o = 32; o > 0; o >>= 1) s += __shfl_down(s, o);
    __shared__ float sm[4];
    if ((t & 63) == 0) sm[t >> 6] = s;
    __syncthreads();
    if (t == 0) {
        float r = sm[0] + sm[1] + sm[2] + sm[3];
        trow[i] = r;
        atomicAdd(&sc[5], (double)r);
    }
}

// ---------------- trans col sums (tcol must be zeroed) ----------------
__global__ void col_sums(const float* __restrict__ T, float* __restrict__ tcol) {
    int j = blockIdx.x * 256 + threadIdx.x;
    int r0 = blockIdx.y * (N / 32);
    float s = 0.f;
    for (int i = 0; i < N / 32; ++i) s += T[(size_t)(r0 + i) * N + j];
    atomicAdd(&tcol[j], s);
}

// ---------------- trans -> bf16 in A-format (Ta) and B-format (Tb) ----------
// A-fmt slot(r,c) = ((r>>4)*(N/8) + (c>>3))*128 + (r&15)*8 + (c&7), holds M[r][c]
// B-fmt slot for (k,n) = A-fmt slot(n,k), holds M[k][n]
__global__ void trans_convert(const float* __restrict__ T,
                              unsigned short* __restrict__ Ta,
                              unsigned short* __restrict__ Tb) {
    int t = threadIdx.x;
    int cb = blockIdx.x * 64 + (t & 63);   // col-block (4 cols)
    int rb = blockIdx.y * 4 + (t >> 6);    // row-block (4 rows)
    int r0 = rb * 4, c0 = cb * 4;
    float vv[4][4];
    #pragma unroll
    for (int i = 0; i < 4; ++i) {
        float4 r4 = *(const float4*)&T[(size_t)(r0 + i) * N + c0];
        vv[i][0] = r4.x; vv[i][1] = r4.y; vv[i][2] = r4.z; vv[i][3] = r4.w;
    }
    #pragma unroll
    for (int i = 0; i < 4; ++i) {
        int r = r0 + i;
        size_t slot = ((size_t)(r >> 4) * (N / 8) + (c0 >> 3)) * 128 + (r & 15) * 8 + (c0 & 7);
        short4 s;
        s.x = (short)f2bf(vv[i][0]); s.y = (short)f2bf(vv[i][1]);
        s.z = (short)f2bf(vv[i][2]); s.w = (short)f2bf(vv[i][3]);
        *(short4*)&Ta[slot] = s;
    }
    #pragma unroll
    for (int j = 0; j < 4; ++j) {
        int n = c0 + j;
        size_t slot = ((size_t)(n >> 4) * (N / 8) + (r0 >> 3)) * 128 + (n & 15) * 8 + (r0 & 7);
        short4 s;
        s.x = (short)f2bf(vv[0][j]); s.y = (short)f2bf(vv[1][j]);
        s.z = (short)f2bf(vv[2][j]); s.w = (short)f2bf(vv[3][j]);
        *(short4*)&Tb[slot] = s;
    }
}

// ---------------- cosine-cost kernels ----------------
template <int SELF>
__global__ __launch_bounds__(256) void cost_kernel(
        const float* __restrict__ EA, const float* __restrict__ EB,
        const float* __restrict__ ea, const float* __restrict__ eb,
        const float* __restrict__ ref_or_trans,
        const float* __restrict__ mu, const float* __restrict__ tsum,
        unsigned short* __restrict__ outD, double* __restrict__ sc) {
    __shared__ float As[16][68];
    __shared__ float Bs[16][68];
    __shared__ double red[256];
    int t = threadIdx.x;
    int tx = t & 15, ty = t >> 4;
    int bi = blockIdx.y * 64, bj = blockIdx.x * 64;
    float acc[4][4] = {};
    for (int kk = 0; kk < D; kk += 16) {
        #pragma unroll
        for (int r = 0; r < 4; ++r) {
            int e = t + 256 * r;
            int ar = e >> 4, ac = e & 15;
            As[ac][ar] = EA[(size_t)(bi + ar) * D + kk + ac];
            Bs[ac][ar] = EB[(size_t)(bj + ar) * D + kk + ac];
        }
        __syncthreads();
        #pragma unroll
        for (int k = 0; k < 16; ++k) {
            float4 av = *(const float4*)&As[k][ty * 4];
            float4 bv = *(const float4*)&Bs[k][tx * 4];
            float a[4] = {av.x, av.y, av.z, av.w};
            float b[4] = {bv.x, bv.y, bv.z, bv.w};
            #pragma unroll
            for (int u = 0; u < 4; ++u)
                #pragma unroll
                for (int v = 0; v < 4; ++v)
                    acc[u][v] = fmaf(a[u], b[v], acc[u][v]);
        }
        __syncthreads();
    }
    float eav[4], ebv[4];
    #pragma unroll
    for (int u = 0; u < 4; ++u) eav[u] = ea[bi + ty * 4 + u];
    #pragma unroll
    for (int v = 0; v < 4; ++v) ebv[v] = eb[bj + tx * 4 + v];

    double l1 = 0.0, l2 = 0.0;
    #pragma unroll
    for (int u = 0; u < 4; ++u) {
        int ri = bi + ty * 4 + u;
        float cv[4];
        #pragma unroll
        for (int v = 0; v < 4; ++v) {
            int ci = bj + tx * 4 + v;
            size_t id = (size_t)ri * N + ci;
            float denom = eav[u] * ebv[v] + FEPS;
            float cosv = acc[u][v] / denom;
            if (SELF) {
                float c = 1.f - expf(-5.f * (1.f - cosv));
                cv[v] = c;
                float rc = ref_or_trans[id];
                float dd = c - rc;
                l1 += (double)(dd * dd * expf(-rc));
                l2 += (double)(c * c) * (double)mu[ci] * (double)tsum[ri];
            } else {
                float c = 1.f - expf(-(1.f - cosv));
                l1 += (double)c * (double)ref_or_trans[id];
            }
        }
        if (SELF) {
            int ci0 = bj + tx * 4;
            size_t slot = ((size_t)(ri >> 4) * (N / 8) + (ci0 >> 3)) * 128 + (ri & 15) * 8 + (ci0 & 7);
            short4 s;
            s.x = (short)f2bf(cv[0] - C0F); s.y = (short)f2bf(cv[1] - C0F);
            s.z = (short)f2bf(cv[2] - C0F); s.w = (short)f2bf(cv[3] - C0F);
            *(short4*)&outD[slot] = s;
        }
    }
    double s1 = block_reduce256(l1, red);
    if (SELF) {
        double s2v = block_reduce256(l2, red);
        if (t == 0) { atomicAdd(&sc[0], s1); atomicAdd(&sc[1], s2v); }
    } else {
        if (t == 0) atomicAdd(&sc[3], s1);
    }
}

// ---------------- bf16 MFMA GEMM, 128x128 tile, 1-barrier dbuf pipeline -----
__device__ __forceinline__ void mfma_step(const char* ard, const char* brd,
                                          f32x4 (&acc)[4][4]) {
    bf16x8 af[4], bfr[4];
    #pragma unroll
    for (int f = 0; f < 4; ++f) {
        af[f]  = *(const bf16x8*)(ard + f * 1024);
        bfr[f] = *(const bf16x8*)(brd + f * 1024);
    }
    #pragma unroll
    for (int mf = 0; mf < 4; ++mf)
        #pragma unroll
        for (int nf = 0; nf < 4; ++nf)
            acc[mf][nf] = __builtin_amdgcn_mfma_f32_16x16x32_bf16(
                af[mf], bfr[nf], acc[mf][nf], 0, 0, 0);
}

// STORE=1: Pd = A@B -> Pdb (bf16, C-fragment-native tiled layout)
// STORE=0: Qd = A@B; epilogue: sc[6]+=Σ tcol[j]*Qd, sc[7]+=Σ trow[i]*Pd,
//          sc[2]+=Σ Pd*Qd
template <int STORE>
__global__ __launch_bounds__(256, 3) void gemm_mfma(
        const unsigned short* __restrict__ Ag, const unsigned short* __restrict__ Bg,
        unsigned short* __restrict__ Pdb,
        const float* __restrict__ trow, const float* __restrict__ tcol,
        double* __restrict__ sc) {
    __shared__ __align__(16) char Abuf[2][8192];
    __shared__ __align__(16) char Bbuf[2][8192];
    __shared__ double red[256];
    const int t = threadIdx.x, l = t & 63;
    // wave id is wave-uniform: force into SGPR so all address bases scalarize
    const int w = __builtin_amdgcn_readfirstlane(t >> 6);
    const int wm = w >> 1, wn = w & 1;
    // XCD-aware swizzle: xcd = lid%8 owns a 4-row band, walks columns
    const int lid = blockIdx.x;
    const int by = (lid & 7) * 4 + ((lid >> 3) & 3);
    const int bx = lid >> 5;
    const size_t grp = (size_t)(N / 8) * 256;  // bytes per 16-row group (all k)

    const char* aG = (const char*)Ag + (size_t)(by * 8 + w * 2) * grp + (size_t)(l * 16);
    const char* bG = (const char*)Bg + (size_t)(bx * 8 + w * 2) * grp + (size_t)(l * 16);

    f32x4 acc[4][4];
    #pragma unroll
    for (int i = 0; i < 4; ++i)
        #pragma unroll
        for (int j = 0; j < 4; ++j)
            acc[i][j] = (f32x4){0.f, 0.f, 0.f, 0.f};

    // prologue: stage chunk 0 -> buf 0
    async16(&Abuf[0][w * 2048],        aG);
    async16(&Abuf[0][w * 2048 + 1024], aG + grp);
    async16(&Bbuf[0][w * 2048],        bG);
    async16(&Bbuf[0][w * 2048 + 1024], bG + grp);

    for (int it = 0; it < N / 32; ++it) {
        __syncthreads();  // drains chunk it staging; retires reads of buf it-1
        const int ph = it & 1, pn = ph ^ 1;
        if (it + 1 < N / 32) {
            const char* a = aG + (size_t)(it + 1) * 1024;
            const char* b = bG + (size_t)(it + 1) * 1024;
            async16(&Abuf[pn][w * 2048],        a);
            async16(&Abuf[pn][w * 2048 + 1024], a + grp);
            async16(&Bbuf[pn][w * 2048],        b);
            async16(&Bbuf[pn][w * 2048 + 1024], b + grp);
        }
        mfma_step(&Abuf[ph][wm * 4096] + l * 16, &Bbuf[ph][wn * 4096] + l * 16, acc);
    }

    const size_t blkbase = (size_t)(by * 32 + bx) * 4096 + (size_t)w * 1024;
    if (STORE) {
        #pragma unroll
        for (int mf = 0; mf < 4; ++mf)
            #pragma unroll
            for (int nf = 0; nf < 4; ++nf) {
                f32x4 a = acc[mf][nf];
                short4 s;
                s.x = (short)f2bf(a[0]); s.y = (short)f2bf(a[1]);
                s.z = (short)f2bf(a[2]); s.w = (short)f2bf(a[3]);
                *(short4*)&Pdb[(blkbase + (mf * 4 + nf) * 64 + l) * 4] = s;
            }
    } else {
        double t1 = 0.0, t2 = 0.0, t3 = 0.0;
        const int quad = l >> 4, lan = l & 15;
        #pragma unroll
        for (int mf = 0; mf < 4; ++mf) {
            const int ib = by * 128 + wm * 64 + mf * 16 + quad * 4;  // row i base
            float4 tr4 = *(const float4*)&trow[ib];
            float trv[4] = {tr4.x, tr4.y, tr4.z, tr4.w};
            #pragma unroll
            for (int nf = 0; nf < 4; ++nf) {
                const int j = bx * 128 + wn * 64 + nf * 16 + lan;    // col j
                const float tcj = tcol[j];
                short4 p = *(const short4*)&Pdb[(blkbase + (mf * 4 + nf) * 64 + l) * 4];
                float pf[4] = {bf2f(p.x), bf2f(p.y), bf2f(p.z), bf2f(p.w)};
                #pragma unroll
                for (int r = 0; r < 4; ++r) {
                    double x = (double)acc[mf][nf][r];
                    t1 += (double)tcj * x;
                    t2 += (double)trv[r] * (double)pf[r];
                    t3 += x * (double)pf[r];
                }
            }
        }
        double s1 = block_reduce256(t1, red);
        double s2 = block_reduce256(t2, red);
        double s3 = block_reduce256(t3, red);
        if (t == 0) {
            atomicAdd(&sc[6], s1);
            atomicAdd(&sc[7], s2);
            atomicAdd(&sc[2], s3);
        }
    }
}

// ---------------- orthogonality: tiled gram partials + finalize -------------
__global__ __launch_bounds__(256) void gram_partial(const float* __restrict__ E,
                                                    float* __restrict__ G) {
    __shared__ float Es[16][132];
    int t = threadIdx.x, tx = t & 15, ty = t >> 4;
    int i0 = blockIdx.x * 128;
    float acc[8][8] = {};
    for (int kk = 0; kk < 128; kk += 16) {
        #pragma unroll
        for (int r = 0; r < 2; ++r) {
            int q = t + 256 * r;
            int row = q >> 5, c4 = (q & 31) * 4;
            *(float4*)&Es[row][c4] = *(const float4*)&E[(size_t)(i0 + kk + row) * D + c4];
        }
        __syncthreads();
        #pragma unroll
        for (int k = 0; k < 16; ++k) {
            float a[8], b[8];
            *(float4*)&a[0] = *(const float4*)&Es[k][ty * 8];
            *(float4*)&a[4] = *(const float4*)&Es[k][ty * 8 + 4];
            *(float4*)&b[0] = *(const float4*)&Es[k][tx * 8];
            *(float4*)&b[4] = *(const float4*)&Es[k][tx * 8 + 4];
            #pragma unroll
            for (int u = 0; u < 8; ++u)
                #pragma unroll
                for (int v = 0; v < 8; ++v)
                    acc[u][v] = fmaf(a[u], b[v], acc[u][v]);
        }
        __syncthreads();
    }
    #pragma unroll
    for (int u = 0; u < 8; ++u)
        #pragma unroll
        for (int v = 0; v < 8; ++v)
            atomicAdd(&G[(size_t)(ty * 8 + u) * D + tx * 8 + v], acc[u][v]);
}

__global__ void orth_final(const float* __restrict__ G, double* __restrict__ sc) {
    __shared__ double red[256];
    const float* g = G + (size_t)blockIdx.x * D * D;
    int t = threadIdx.x;
    double s = 0.0;
    for (int q = t; q < D * D; q += 256) {
        float v = g[q] - ((q % (D + 1)) == 0 ? 1.f : 0.f);
        s += (double)v * (double)v;
    }
    double r = block_reduce256(s, red);
    if (t == 0) atomicAdd(&sc[4], r);
}

// ---------------- finalize ----------------
__global__ void finalize(const double* __restrict__ sc, float* __restrict__ out) {
    if (threadIdx.x == 0) {
        const double C0 = (double)C0F;
        double S = sc[5];
        double pq = C0 * C0 * S * S + C0 * sc[6] + C0 * sc[7] + sc[2];
        out[0] = (float)(sc[1] - 2.0 * pq);  // d_gw
        out[1] = (float)sc[3];               // d_w
        out[2] = (float)(sc[0] + sc[4]);     // regularizer
    }
}

extern "C" void kernel_launch(void* const* d_in, const int* in_sizes, int n_in,
                              void* d_out, int out_size, void* d_ws, size_t ws_size,
                              hipStream_t stream) {
    const int*   index1 = (const int*)d_in[0];
    const int*   index2 = (const int*)d_in[1];
    const float* trans  = (const float*)d_in[2];
    const float* mu_s   = (const float*)d_in[3];
    const float* mu_t   = (const float*)d_in[4];
    const float* cost1  = (const float*)d_in[5];
    const float* cost2  = (const float*)d_in[6];
    const float* emb1_w = (const float*)d_in[7];
    const float* emb2_w = (const float*)d_in[8];
    float* out = (float*)d_out;

    char* w = (char*)d_ws;
    double* sc  = (double*)w;                          // 8 doubles @0
    float* tcol = (float*)(w + 256);                   // 16 KB (zeroed)
    float* trow = (float*)(w + 16640);                 // 16 KB
    float* e1   = (float*)(w + 33024);                 // 16 KB
    float* e2   = (float*)(w + 49408);                 // 16 KB
    float* E1   = (float*)(w + 65792);                 // 2 MB
    float* E2   = (float*)(w + 2162944);               // 2 MB
    unsigned short* Ds  = (unsigned short*)(w + 4260096);    // 32 MB (Δs, then Δt)
    unsigned short* Ta  = (unsigned short*)(w + 37814528);   // 32 MB trans A-fmt
    unsigned short* Tb  = (unsigned short*)(w + 71368960);   // 32 MB trans B-fmt
    unsigned short* Pdb = (unsigned short*)(w + 104923392);  // 32 MB Pd bf16 (C-layout)
    float* Gbuf = (float*)(w + 37814528);              // 128 KB, overlays Ta (dead after gemm2)

    hipMemsetAsync(d_ws, 0, 16640, stream);  // sc + tcol

    gather_energy<<<N, D, 0, stream>>>(emb1_w, index1, E1, e1);
    gather_energy<<<N, D, 0, stream>>>(emb2_w, index2, E2, e2);
    row_sums<<<N, 256, 0, stream>>>(trans, trow, sc);
    col_sums<<<dim3(16, 32), 256, 0, stream>>>(trans, tcol);
    trans_convert<<<dim3(16, 256), 256, 0, stream>>>(trans, Ta, Tb);

    dim3 g64(N / 64, N / 64);

    // Δs (+ sim1 -> sc[0], f1-term -> sc[1])
    cost_kernel<1><<<g64, 256, 0, stream>>>(E1, E1, e1, e1, cost1, mu_s, trow, Ds, sc);
    // Pd = Δs @ trans
    gemm_mfma<1><<<1024, 256, 0, stream>>>(Ds, Tb, Pdb, nullptr, nullptr, sc);
    // Δt (+ sim2 -> sc[0], f2-term -> sc[1]); reuses Ds
    cost_kernel<1><<<g64, 256, 0, stream>>>(E2, E2, e2, e2, cost2, mu_t, tcol, Ds, sc);
    // Qd = trans @ Δt; fused epilogue (sc[2], sc[6], sc[7])
    gemm_mfma<0><<<1024, 256, 0, stream>>>(Ta, Ds, Pdb, trow, tcol, sc);
    // d_w -> sc[3]
    cost_kernel<0><<<g64, 256, 0, stream>>>(E1, E2, e1, e2, trans, nullptr, nullptr, nullptr, sc);
    // orthogonality
    hipMemsetAsync(Gbuf, 0, 2 * D * D * sizeof(float), stream);
    gram_partial<<<32, 256, 0, stream>>>(E1, Gbuf);
    gram_partial<<<32, 256, 0, stream>>>(E2, Gbuf + D * D);
    orth_final<<<2, 256, 0, stream>>>(Gbuf, sc);

    finalize<<<1, 64, 0, stream>>>(sc, out);
}